// Round 3
// baseline (5843.737 us; speedup 1.0000x reference)
//
#include <hip/hip_runtime.h>

// ---------------------------------------------------------------------------
// QMon (monDEQ) full pipeline, fp32.
//  conv1(8x8,s4)+relu -> conv2(4x4,s2)+relu -> monDEQ PR solver (freq domain)
//  -> border crop -> fc1+relu -> fc2
// Round 3: persistent per-batch solver (1 dispatch, all state in LDS,
//          local early exit), LDS-staged coalesced conv1.
// ---------------------------------------------------------------------------

#define NB 256
#define NCH 64
#define NP 81
#define NIMG (NB*NCH)
#define TOLF 1e-5f
#define MAXIT 50
#define NCAN 41                       // canonical freqs: {0..4} U {9..44}
#define CANON(l) ((l) < 5 ? (l) : (l) + 4)

__constant__ float COS9[9] = {
  1.0f, 0.76604444311897803f, 0.17364817766693041f, -0.5f,
  -0.93969262078590843f, -0.93969262078590843f, -0.5f,
  0.17364817766693041f, 0.76604444311897803f };
__constant__ float SIN9[9] = {
  0.0f, 0.64278760968653936f, 0.98480775301220802f, 0.86602540378443871f,
  0.34202014332566877f, -0.34202014332566877f, -0.86602540378443871f,
  -0.98480775301220802f, -0.64278760968653936f };

// ---------------- norm of A_w ----------------------------------------------
__global__ __launch_bounds__(256) void k_norm(const float* __restrict__ Aw,
                                              float* __restrict__ sc) {
    __shared__ float red[256];
    float s = 0.f;
    for (int i = threadIdx.x; i < 64*64*9; i += 256) { float a = Aw[i]; s += a*a; }
    red[threadIdx.x] = s; __syncthreads();
    for (int w = 128; w > 0; w >>= 1) {
        if (threadIdx.x < w) red[threadIdx.x] += red[threadIdx.x + w];
        __syncthreads();
    }
    if (threadIdx.x == 0) { float n = sqrtf(red[0]); sc[0] = n; sc[1] = 1.f/n; }
}

// ---------------- conv1: (256,4,84,84)->(256,32,20,20), k8 s4, relu, x/255 --
// block = one image, 512 threads, 2-pass LDS staging (2 in-channels/pass).
__global__ __launch_bounds__(512) void k_conv1(const float* __restrict__ x,
                                               const float* __restrict__ w,
                                               const float* __restrict__ bb,
                                               float* __restrict__ y) {
    __shared__ float xl[2*7056];              // 56,448 B
    int b = blockIdx.x, tid = threadIdx.x;
    float acc[32];
    #pragma unroll
    for (int o = 0; o < 32; ++o) acc[o] = 0.f;
    int p = tid, oy = p/20, ox = p%20;        // valid if p<400
    for (int cp = 0; cp < 2; ++cp) {
        __syncthreads();
        const float4* xg = (const float4*)(x + b*28224 + cp*14112);
        for (int i = tid; i < 3528; i += 512) ((float4*)xl)[i] = xg[i];
        __syncthreads();
        if (p < 400) {
            #pragma unroll
            for (int ci = 0; ci < 2; ++ci)
            #pragma unroll
            for (int ky = 0; ky < 8; ++ky) {
                const float* xr = xl + ci*7056 + (oy*4+ky)*84 + ox*4;
                float4 x0 = *(const float4*)xr;
                float4 x1 = *(const float4*)(xr+4);
                const float* wr = w + (cp*2+ci)*64 + ky*8;   // + o*256
                #pragma unroll
                for (int o = 0; o < 32; ++o) {
                    const float* wo = wr + o*256;            // uniform -> s_load
                    acc[o] += x0.x*wo[0] + x0.y*wo[1] + x0.z*wo[2] + x0.w*wo[3]
                            + x1.x*wo[4] + x1.y*wo[5] + x1.z*wo[6] + x1.w*wo[7];
                }
            }
        }
    }
    if (p < 400) {
        #pragma unroll
        for (int o = 0; o < 32; ++o)
            y[b*12800 + o*400 + p] = fmaxf(acc[o]*(1.f/255.f) + bb[o], 0.f);
    }
}

// ---------------- conv2: (256,32,20,20)->(256,64,9,9), k4 s2, relu ---------
__global__ __launch_bounds__(256) void k_conv2(const float* __restrict__ h1,
                                               const float* __restrict__ w,
                                               const float* __restrict__ bb,
                                               float* __restrict__ h2) {
    int b = blockIdx.x;
    __shared__ float hl[12800];
    for (int i = threadIdx.x; i < 12800; i += 256) hl[i] = h1[b*12800 + i];
    __syncthreads();
    for (int idx = threadIdx.x; idx < 5184; idx += 256) {
        int o = idx/81, p = idx%81, oy = p/9, ox = p%9;
        float acc = 0.f;
        const float* wo = w + o*512;
        for (int ci = 0; ci < 32; ci++) {
            const float* hb = hl + ci*400 + oy*40 + ox*2;
            const float* wb = wo + ci*16;
            #pragma unroll
            for (int ky = 0; ky < 4; ky++)
            #pragma unroll
            for (int kx = 0; kx < 4; kx++)
                acc += hb[ky*20 + kx] * wb[ky*4 + kx];
        }
        h2[b*5184 + idx] = fmaxf(acc + bb[o], 0.f);
    }
}

// ---------------- bias = circ_conv3x3(h2, U_w) + U_b -----------------------
__global__ __launch_bounds__(256) void k_bias(const float* __restrict__ h2,
                                              const float* __restrict__ Uw,
                                              const float* __restrict__ Ub,
                                              float* __restrict__ bias) {
    int b = blockIdx.x;
    __shared__ float hl[5184];
    for (int i = threadIdx.x; i < 5184; i += 256) hl[i] = h2[b*5184 + i];
    __syncthreads();
    for (int idx = threadIdx.x; idx < 5184; idx += 256) {
        int o = idx/81, p = idx%81, i0 = p/9, j0 = p%9;
        int im = (i0+8)%9, ip = (i0+1)%9, jm = (j0+8)%9, jp = (j0+1)%9;
        int r0 = im*9, r1 = i0*9, r2 = ip*9;
        float acc = 0.f;
        const float* wo = Uw + o*576;
        for (int ci = 0; ci < 64; ci++) {
            const float* hb = hl + ci*81;
            const float* wb = wo + ci*9;
            acc += hb[r0+jm]*wb[0] + hb[r0+j0]*wb[1] + hb[r0+jp]*wb[2]
                 + hb[r1+jm]*wb[3] + hb[r1+j0]*wb[4] + hb[r1+jp]*wb[5]
                 + hb[r2+jm]*wb[6] + hb[r2+j0]*wb[7] + hb[r2+jp]*wb[8];
        }
        bias[b*5184 + idx] = acc + Ub[o];
    }
}

// ---------------- Af(f) for canonical f only -------------------------------
__global__ __launch_bounds__(256) void k_af(const float* __restrict__ Aw,
                                            const float* __restrict__ sc,
                                            float2* __restrict__ Af) {
    int l = blockIdx.x; int f = CANON(l);
    int x = f/9, y = f%9;
    float inv = sc[1];
    for (int pr = threadIdx.x; pr < 4096; pr += 256) {
        const float* a = Aw + pr*9;
        float re = 0.f, im = 0.f;
        #pragma unroll
        for (int dx = 0; dx < 3; dx++)
        #pragma unroll
        for (int dy = 0; dy < 3; dy++) {
            int tt = (x*(dx+8) + y*(dy+8)) % 9;
            float v = a[dx*3+dy] * inv;
            re += v * COS9[tt]; im += v * SIN9[tt];
        }
        Af[f*4096 + pr] = make_float2(re, im);
    }
}

// ---------------- M = 1.1 I + g A^H A ; W^T = (0.9 I - g A^H A)^T ----------
__global__ __launch_bounds__(256) void k_mw(const float2* __restrict__ Af,
                                            const float* __restrict__ gp,
                                            float2* __restrict__ Mmat,
                                            float2* __restrict__ WmT) {
    int l = blockIdx.x; int f = CANON(l);
    float g = gp[0];
    __shared__ float2 Al[4096];
    for (int i = threadIdx.x; i < 4096; i += 256) Al[i] = Af[f*4096 + i];
    __syncthreads();
    for (int e = threadIdx.x; e < 4096; e += 256) {
        int i = e >> 6, j = e & 63;
        float sr = 0.f, si = 0.f;
        for (int o = 0; o < 64; o++) {
            float2 a = Al[o*64 + i], b = Al[o*64 + j];
            sr += a.x*b.x + a.y*b.y;
            si += a.x*b.y - a.y*b.x;
        }
        Mmat[f*4096 + e] = make_float2((i==j ? 1.1f : 0.f) + g*sr, g*si);
        WmT [f*4096 + j*64 + i] = make_float2((i==j ? 0.9f : 0.f) - g*sr, -g*si);
    }
}

// ---------------- in-place Gauss-Jordan inverse, conflict-free -------------
// LDS rows padded to 65 float2. Writes back transposed: Mio[f][c][o].
__global__ __launch_bounds__(256) void k_inv(float2* __restrict__ Mio) {
    int l = blockIdx.x; int f = CANON(l);
    __shared__ float2 M[64*65];
    __shared__ float2 rowk[64];
    __shared__ float2 fcol[64];
    int tid = threadIdx.x;
    float2* Mg = Mio + f*4096;
    for (int e = tid; e < 4096; e += 256) M[(e>>6)*65 + (e&63)] = Mg[e];
    __syncthreads();
    int j = tid & 63, ig = tid >> 6;
    for (int k = 0; k < 64; k++) {
        if (ig == 0) {
            float2 d = M[k*65 + k];
            float den = 1.f / (d.x*d.x + d.y*d.y);
            float pr = d.x*den, pi = -d.y*den;
            float2 m = M[k*65 + j];
            rowk[j] = (j == k) ? make_float2(pr, pi)
                               : make_float2(m.x*pr - m.y*pi, m.x*pi + m.y*pr);
        } else if (ig == 1) {
            fcol[j] = M[j*65 + k];
        }
        __syncthreads();
        #pragma unroll 4
        for (int s = 0; s < 16; s++) {
            int i = (ig << 4) + s;
            if (i == k) {
                M[i*65 + j] = rowk[j];
            } else {
                float2 fi = fcol[i];
                if (j == k) {
                    float2 rk = rowk[k];
                    M[i*65 + j] = make_float2(-(fi.x*rk.x - fi.y*rk.y),
                                              -(fi.x*rk.y + fi.y*rk.x));
                } else {
                    float2 r = rowk[j]; float2 m = M[i*65 + j];
                    M[i*65 + j] = make_float2(m.x - (fi.x*r.x - fi.y*r.y),
                                              m.y - (fi.x*r.y + fi.y*r.x));
                }
            }
        }
        __syncthreads();
    }
    for (int e = tid; e < 4096; e += 256) {
        int i2 = e >> 6, j2 = e & 63;
        Mio[f*4096 + j2*64 + i2] = M[i2*65 + j2];
    }
}

// ---------------- persistent per-batch PR solver ---------------------------
// 256 blocks (1 batch each) x 512 threads. All state in LDS.
// V layout: [f][c][o] (transposed), canonical f only.
__global__ __launch_bounds__(512, 1) void k_solver(const float* __restrict__ bias,
                                                   const float2* __restrict__ Minv,
                                                   const float2* __restrict__ Wm,
                                                   float* __restrict__ zc) {
    __shared__ float biasl[5184], zl[5184], t12l[5184];   // 62,208 B
    __shared__ float2 TY[NCAN*64], YL[NCAN*64];           // 41,984 B
    __shared__ float2 SS[32*81];                          // 20,736 B
    __shared__ float red[18];
    int b = blockIdx.x, tid = threadIdx.x;
    for (int i = tid; i < 5184; i += 512) {
        float bv = bias[b*5184 + i];
        biasl[i] = bv; zl[i] = 0.f; t12l[i] = bv;         // u12=0 -> t12=bias
    }
    int img = tid & 31, th = tid >> 5;     // FFT mapping: 32 imgs x 16 slots
    int o = tid & 63, fg = tid >> 6;       // matvec mapping: 64 outs x 8 waves
    bool finalpass = false;
    int it = 0;
    for (;;) {
        __syncthreads();
        const float* src = finalpass ? zl : t12l;
        // ---- forward FFT2: src -> TY (canonical freqs) ----
        for (int half = 0; half < 2; ++half) {
            int ch = half*32 + img;
            const float* trow = src + ch*81;
            for (int k = 0; k < 6; ++k) {
                int idx = th + 16*k;
                if (idx < 81) {
                    int r = idx/9, ky = idx%9;
                    float sr = 0.f, si = 0.f; int tt = 0;
                    #pragma unroll
                    for (int xx = 0; xx < 9; ++xx) {
                        float v = trow[r*9 + xx];
                        sr += v*COS9[tt]; si -= v*SIN9[tt];
                        tt += ky; if (tt >= 9) tt -= 9;
                    }
                    SS[img*81 + idx] = make_float2(sr, si);
                }
            }
            __syncthreads();
            for (int k = 0; k < 3; ++k) {
                int l = th + 16*k;
                if (l < NCAN) {
                    int f = CANON(l); int kx = f/9, ky = f%9;
                    float fr = 0.f, fi = 0.f; int tt = 0;
                    #pragma unroll
                    for (int r = 0; r < 9; ++r) {
                        float2 s = SS[img*81 + r*9 + ky];
                        float c = COS9[tt], sn = SIN9[tt];
                        fr += s.x*c + s.y*sn; fi += s.y*c - s.x*sn;
                        tt += kx; if (tt >= 9) tt -= 9;
                    }
                    TY[l*64 + ch] = make_float2(fr, fi);
                }
            }
            __syncthreads();
        }
        // ---- per-frequency matvec: YL = V * TY ----
        {
            const float2* V = finalpass ? Wm : Minv;
            for (int l = fg; l < NCAN; l += 8) {
                const float2* Vg = V + CANON(l)*4096 + o;
                float2 a = make_float2(0.f, 0.f);
                #pragma unroll 8
                for (int c = 0; c < 64; ++c) {
                    float2 v = Vg[c*64];
                    float2 t = TY[l*64 + c];
                    a.x += v.x*t.x - v.y*t.y;
                    a.y += v.x*t.y + v.y*t.x;
                }
                YL[l*64 + o] = a;
            }
        }
        __syncthreads();
        // ---- inverse FFT2 (mirrors inline) + update / final write ----
        float d2 = 0.f, n2 = 0.f;
        for (int half = 0; half < 2; ++half) {
            int ch = half*32 + img;
            for (int k = 0; k < 6; ++k) {
                int idx = th + 16*k;
                if (idx < 81) {
                    int r = idx/9, ky = idx%9;
                    float sr = 0.f, si = 0.f; int tt = 0;
                    #pragma unroll
                    for (int kx = 0; kx < 9; ++kx) {
                        int f = kx*9 + ky;
                        int fm = f, cj = 0;
                        if (!(f < 5 || (f >= 9 && f < 45))) {
                            fm = ((9-kx)%9)*9 + (9-ky)%9; cj = 1;
                        }
                        int l = (fm < 5) ? fm : fm - 4;
                        float2 a = YL[l*64 + ch];
                        float ay = cj ? -a.y : a.y;
                        float c = COS9[tt], sn = SIN9[tt];
                        sr += a.x*c - ay*sn;
                        si += a.x*sn + ay*c;
                        tt += r; if (tt >= 9) tt -= 9;
                    }
                    SS[img*81 + idx] = make_float2(sr, si);
                }
            }
            __syncthreads();
            for (int k = 0; k < 6; ++k) {
                int p = th + 16*k;
                if (p < 81) {
                    int r = p/9, xc = p%9;
                    float yr = 0.f; int tt = 0;
                    #pragma unroll
                    for (int ky = 0; ky < 9; ++ky) {
                        float2 a = SS[img*81 + r*9 + ky];
                        yr += a.x*COS9[tt] - a.y*SIN9[tt];
                        tt += xc; if (tt >= 9) tt -= 9;
                    }
                    yr *= (1.f/81.f);
                    bool interior = (r >= 1 && r <= 7 && xc >= 1 && xc <= 7);
                    int gi = ch*81 + p;
                    if (!finalpass) {
                        float u12v = t12l[gi] - biasl[gi];
                        float un = 2.f*yr - u12v;
                        float zn = interior ? fmaxf(un, 0.f) : 0.f;
                        float zo = zl[gi];
                        float d = zn - zo;
                        d2 += d*d; n2 += zn*zn;
                        zl[gi] = zn;
                        t12l[gi] = 2.f*zn - un + biasl[gi];
                    } else if (interior) {
                        float zv = fmaxf(yr + biasl[gi], 0.f);
                        zc[b*3136 + ch*49 + (r-1)*7 + (xc-1)] = zv;
                    }
                }
            }
            __syncthreads();
        }
        if (finalpass) break;
        // ---- convergence test (block-local, deterministic) ----
        #pragma unroll
        for (int off = 32; off > 0; off >>= 1) {
            d2 += __shfl_xor(d2, off);
            n2 += __shfl_xor(n2, off);
        }
        int wv = tid >> 6;
        if ((tid & 63) == 0) { red[wv*2] = d2; red[wv*2+1] = n2; }
        __syncthreads();
        if (tid == 0) {
            float td = 0.f, tn = 0.f;
            for (int q = 0; q < 8; ++q) { td += red[q*2]; tn += red[q*2+1]; }
            red[16] = (sqrtf(td) <= TOLF*(1e-6f + sqrtf(tn))) ? 1.f : 0.f;
        }
        __syncthreads();
        bool stop = (red[16] != 0.f);
        ++it;
        if (stop || it >= MAXIT) finalpass = true;
    }
}

// ---------------- fc1: (256x3136)x(512x3136)^T + b, relu -------------------
__global__ __launch_bounds__(256) void k_fc1(const float* __restrict__ A,
                                             const float* __restrict__ W,
                                             const float* __restrict__ bb,
                                             float* __restrict__ H) {
    int bt = blockIdx.x >> 5, ot = blockIdx.x & 31;
    int b0 = bt*16, o0 = ot*16;
    __shared__ float At[16][65], Bt[16][65];
    int tid = threadIdx.x;
    int row = tid >> 6, col = tid & 63;
    int tb = tid >> 4, to = tid & 15;
    float acc = 0.f;
    for (int k0 = 0; k0 < 3136; k0 += 64) {
        #pragma unroll
        for (int s = 0; s < 4; s++) {
            int rr = row + s*4;
            At[rr][col] = A[(b0+rr)*3136 + k0 + col];
            Bt[rr][col] = W[(o0+rr)*3136 + k0 + col];
        }
        __syncthreads();
        #pragma unroll
        for (int kk = 0; kk < 64; kk++)
            acc += At[tb][kk] * Bt[to][kk];
        __syncthreads();
    }
    H[(b0+tb)*512 + o0+to] = fmaxf(acc + bb[o0+to], 0.f);
}

// ---------------- fc2: (256x512)x(18x512)^T + b ----------------------------
__global__ __launch_bounds__(256) void k_fc2(const float* __restrict__ H,
                                             const float* __restrict__ W,
                                             const float* __restrict__ bb,
                                             float* __restrict__ out) {
    int idx = blockIdx.x*256 + threadIdx.x;
    if (idx >= 4608) return;
    int b = idx/18, o = idx%18;
    const float* h = H + b*512;
    const float* w = W + o*512;
    float acc = 0.f;
    for (int k = 0; k < 512; k++) acc += h[k]*w[k];
    out[idx] = acc + bb[o];
}

// ---------------------------------------------------------------------------
extern "C" void kernel_launch(void* const* d_in, const int* in_sizes, int n_in,
                              void* d_out, int out_size, void* d_ws, size_t ws_size,
                              hipStream_t stream) {
    (void)in_sizes; (void)n_in; (void)out_size; (void)ws_size;
    const float* x   = (const float*)d_in[0];
    const float* c1w = (const float*)d_in[1];
    const float* c1b = (const float*)d_in[2];
    const float* c2w = (const float*)d_in[3];
    const float* c2b = (const float*)d_in[4];
    const float* Uw  = (const float*)d_in[5];
    const float* Ub  = (const float*)d_in[6];
    const float* Aw  = (const float*)d_in[7];
    const float* gp  = (const float*)d_in[8];
    const float* f1w = (const float*)d_in[9];
    const float* f1b = (const float*)d_in[10];
    const float* f2w = (const float*)d_in[11];
    const float* f2b = (const float*)d_in[12];

    float* ws = (float*)d_ws;
    float*  h1   = ws + 0;                       // 3,276,800 f
    float*  h2   = ws + 3276800;                 // 1,327,104 f
    float*  bias = ws + 4603904;                 // 1,327,104 f
    float2* Af   = (float2*)(ws + 5931008);      // 331,776 c2 (sparse canonical)
    float2* Minv = (float2*)(ws + 6594560);      // 331,776 c2
    float2* WmT  = (float2*)(ws + 7258112);      // 331,776 c2
    float*  zc   = ws + 7921664;                 // 802,816 f
    float*  hfc  = ws + 8724480;                 // 131,072 f
    float*  sc   = ws + 8855552;                 // 2 f

    k_norm  <<<1,   256, 0, stream>>>(Aw, sc);
    k_conv1 <<<256, 512, 0, stream>>>(x, c1w, c1b, h1);
    k_conv2 <<<256, 256, 0, stream>>>(h1, c2w, c2b, h2);
    k_bias  <<<256, 256, 0, stream>>>(h2, Uw, Ub, bias);
    k_af    <<<NCAN,256, 0, stream>>>(Aw, sc, Af);
    k_mw    <<<NCAN,256, 0, stream>>>(Af, gp, Minv, WmT);
    k_inv   <<<NCAN,256, 0, stream>>>(Minv);
    k_solver<<<256, 512, 0, stream>>>(bias, Minv, WmT, zc);
    k_fc1   <<<512, 256, 0, stream>>>(zc, f1w, f1b, hfc);
    k_fc2   <<<18,  256, 0, stream>>>(hfc, f2w, f2b, (float*)d_out);
}

// Round 4
// 2669.195 us; speedup vs baseline: 2.1893x; 2.1893x over previous
//
#include <hip/hip_runtime.h>

// ---------------------------------------------------------------------------
// QMon (monDEQ) full pipeline, fp32.
//  conv1(8x8,s4)+relu -> conv2(4x4,s2)+relu -> monDEQ PR solver (freq domain)
//  -> border crop -> fc1+relu -> fc2
// Round 4: back to split per-iteration kernels (round-2 structure) with:
//   - LDS-free k_mv (lane=output, scalar T loads), no flag/err logic
//   - k_fuse with LDS twiddle-product table, fixed 50 iterations
//   - fused conv2+bias kernel, fast conv1 (round-3)
// ---------------------------------------------------------------------------

#define NB 256
#define NCH 64
#define NP 81
#define NIMG (NB*NCH)
#define MAXIT 50
#define NCAN 41                       // canonical freqs: {0..4} U {9..44}
#define CANON(l) ((l) < 5 ? (l) : (l) + 4)

__constant__ float COS9[9] = {
  1.0f, 0.76604444311897803f, 0.17364817766693041f, -0.5f,
  -0.93969262078590843f, -0.93969262078590843f, -0.5f,
  0.17364817766693041f, 0.76604444311897803f };
__constant__ float SIN9[9] = {
  0.0f, 0.64278760968653936f, 0.98480775301220802f, 0.86602540378443871f,
  0.34202014332566877f, -0.34202014332566877f, -0.86602540378443871f,
  -0.98480775301220802f, -0.64278760968653936f };

// ---------------- norm of A_w ----------------------------------------------
__global__ __launch_bounds__(256) void k_norm(const float* __restrict__ Aw,
                                              float* __restrict__ sc) {
    __shared__ float red[256];
    float s = 0.f;
    for (int i = threadIdx.x; i < 64*64*9; i += 256) { float a = Aw[i]; s += a*a; }
    red[threadIdx.x] = s; __syncthreads();
    for (int w = 128; w > 0; w >>= 1) {
        if (threadIdx.x < w) red[threadIdx.x] += red[threadIdx.x + w];
        __syncthreads();
    }
    if (threadIdx.x == 0) { float n = sqrtf(red[0]); sc[0] = n; sc[1] = 1.f/n; }
}

// ---------------- conv1: (256,4,84,84)->(256,32,20,20), k8 s4, relu, x/255 --
__global__ __launch_bounds__(512) void k_conv1(const float* __restrict__ x,
                                               const float* __restrict__ w,
                                               const float* __restrict__ bb,
                                               float* __restrict__ y) {
    __shared__ float xl[2*7056];
    int b = blockIdx.x, tid = threadIdx.x;
    float acc[32];
    #pragma unroll
    for (int o = 0; o < 32; ++o) acc[o] = 0.f;
    int p = tid, oy = p/20, ox = p%20;
    for (int cp = 0; cp < 2; ++cp) {
        __syncthreads();
        const float4* xg = (const float4*)(x + b*28224 + cp*14112);
        for (int i = tid; i < 3528; i += 512) ((float4*)xl)[i] = xg[i];
        __syncthreads();
        if (p < 400) {
            #pragma unroll
            for (int ci = 0; ci < 2; ++ci)
            #pragma unroll
            for (int ky = 0; ky < 8; ++ky) {
                const float* xr = xl + ci*7056 + (oy*4+ky)*84 + ox*4;
                float4 x0 = *(const float4*)xr;
                float4 x1 = *(const float4*)(xr+4);
                const float* wr = w + (cp*2+ci)*64 + ky*8;
                #pragma unroll
                for (int o = 0; o < 32; ++o) {
                    const float* wo = wr + o*256;
                    acc[o] += x0.x*wo[0] + x0.y*wo[1] + x0.z*wo[2] + x0.w*wo[3]
                            + x1.x*wo[4] + x1.y*wo[5] + x1.z*wo[6] + x1.w*wo[7];
                }
            }
        }
    }
    if (p < 400) {
        #pragma unroll
        for (int o = 0; o < 32; ++o)
            y[b*12800 + o*400 + p] = fmaxf(acc[o]*(1.f/255.f) + bb[o], 0.f);
    }
}

// ---------------- fused conv2 + circular bias conv --------------------------
// conv2: (32,20,20)->(64,9,9) k4 s2 relu (kept in LDS);
// bias = circ_conv3x3(h2, U_w) + U_b
__global__ __launch_bounds__(256) void k_cvb(const float* __restrict__ h1,
                                             const float* __restrict__ w2,
                                             const float* __restrict__ b2,
                                             const float* __restrict__ Uw,
                                             const float* __restrict__ Ub,
                                             float* __restrict__ bias) {
    int b = blockIdx.x;
    __shared__ float hl[12800];
    __shared__ float h2l[5184];
    for (int i = threadIdx.x; i < 12800; i += 256) hl[i] = h1[b*12800 + i];
    __syncthreads();
    for (int idx = threadIdx.x; idx < 5184; idx += 256) {
        int o = idx/81, p = idx%81, oy = p/9, ox = p%9;
        float acc = 0.f;
        const float* wo = w2 + o*512;
        for (int ci = 0; ci < 32; ci++) {
            const float* hb = hl + ci*400 + oy*40 + ox*2;
            const float* wb = wo + ci*16;
            #pragma unroll
            for (int ky = 0; ky < 4; ky++)
            #pragma unroll
            for (int kx = 0; kx < 4; kx++)
                acc += hb[ky*20 + kx] * wb[ky*4 + kx];
        }
        h2l[idx] = fmaxf(acc + b2[o], 0.f);
    }
    __syncthreads();
    for (int idx = threadIdx.x; idx < 5184; idx += 256) {
        int o = idx/81, p = idx%81, i0 = p/9, j0 = p%9;
        int im = (i0+8)%9, ip = (i0+1)%9, jm = (j0+8)%9, jp = (j0+1)%9;
        int r0 = im*9, r1 = i0*9, r2 = ip*9;
        float acc = 0.f;
        const float* wo = Uw + o*576;
        for (int ci = 0; ci < 64; ci++) {
            const float* hb = h2l + ci*81;
            const float* wb = wo + ci*9;
            acc += hb[r0+jm]*wb[0] + hb[r0+j0]*wb[1] + hb[r0+jp]*wb[2]
                 + hb[r1+jm]*wb[3] + hb[r1+j0]*wb[4] + hb[r1+jp]*wb[5]
                 + hb[r2+jm]*wb[6] + hb[r2+j0]*wb[7] + hb[r2+jp]*wb[8];
        }
        bias[b*5184 + idx] = acc + Ub[o];
    }
}

// ---------------- Af(f) for canonical f only -------------------------------
__global__ __launch_bounds__(256) void k_af(const float* __restrict__ Aw,
                                            const float* __restrict__ sc,
                                            float2* __restrict__ Af) {
    int l = blockIdx.x; int f = CANON(l);
    int x = f/9, y = f%9;
    float inv = sc[1];
    for (int pr = threadIdx.x; pr < 4096; pr += 256) {
        const float* a = Aw + pr*9;
        float re = 0.f, im = 0.f;
        #pragma unroll
        for (int dx = 0; dx < 3; dx++)
        #pragma unroll
        for (int dy = 0; dy < 3; dy++) {
            int tt = (x*(dx+8) + y*(dy+8)) % 9;
            float v = a[dx*3+dy] * inv;
            re += v * COS9[tt]; im += v * SIN9[tt];
        }
        Af[f*4096 + pr] = make_float2(re, im);
    }
}

// ---------------- M = 1.1 I + g A^H A ; W^T = (0.9 I - g A^H A)^T ----------
__global__ __launch_bounds__(256) void k_mw(const float2* __restrict__ Af,
                                            const float* __restrict__ gp,
                                            float2* __restrict__ Mmat,
                                            float2* __restrict__ WmT) {
    int l = blockIdx.x; int f = CANON(l);
    float g = gp[0];
    __shared__ float2 Al[4096];
    for (int i = threadIdx.x; i < 4096; i += 256) Al[i] = Af[f*4096 + i];
    __syncthreads();
    for (int e = threadIdx.x; e < 4096; e += 256) {
        int i = e >> 6, j = e & 63;
        float sr = 0.f, si = 0.f;
        for (int o = 0; o < 64; o++) {
            float2 a = Al[o*64 + i], b = Al[o*64 + j];
            sr += a.x*b.x + a.y*b.y;
            si += a.x*b.y - a.y*b.x;
        }
        Mmat[f*4096 + e] = make_float2((i==j ? 1.1f : 0.f) + g*sr, g*si);
        WmT [f*4096 + j*64 + i] = make_float2((i==j ? 0.9f : 0.f) - g*sr, -g*si);
    }
}

// ---------------- in-place Gauss-Jordan inverse, conflict-free -------------
// LDS rows padded to 65 float2. Writes back transposed: Mio[f][c][o].
__global__ __launch_bounds__(256) void k_inv(float2* __restrict__ Mio) {
    int l = blockIdx.x; int f = CANON(l);
    __shared__ float2 M[64*65];
    __shared__ float2 rowk[64];
    __shared__ float2 fcol[64];
    int tid = threadIdx.x;
    float2* Mg = Mio + f*4096;
    for (int e = tid; e < 4096; e += 256) M[(e>>6)*65 + (e&63)] = Mg[e];
    __syncthreads();
    int j = tid & 63, ig = tid >> 6;
    for (int k = 0; k < 64; k++) {
        if (ig == 0) {
            float2 d = M[k*65 + k];
            float den = 1.f / (d.x*d.x + d.y*d.y);
            float pr = d.x*den, pi = -d.y*den;
            float2 m = M[k*65 + j];
            rowk[j] = (j == k) ? make_float2(pr, pi)
                               : make_float2(m.x*pr - m.y*pi, m.x*pi + m.y*pr);
        } else if (ig == 1) {
            fcol[j] = M[j*65 + k];
        }
        __syncthreads();
        #pragma unroll 4
        for (int s = 0; s < 16; s++) {
            int i = (ig << 4) + s;
            if (i == k) {
                M[i*65 + j] = rowk[j];
            } else {
                float2 fi = fcol[i];
                if (j == k) {
                    float2 rk = rowk[k];
                    M[i*65 + j] = make_float2(-(fi.x*rk.x - fi.y*rk.y),
                                              -(fi.x*rk.y + fi.y*rk.x));
                } else {
                    float2 r = rowk[j]; float2 m = M[i*65 + j];
                    M[i*65 + j] = make_float2(m.x - (fi.x*r.x - fi.y*r.y),
                                              m.y - (fi.x*r.y + fi.y*r.x));
                }
            }
        }
        __syncthreads();
    }
    for (int e = tid; e < 4096; e += 256) {
        int i2 = e >> 6, j2 = e & 63;
        Mio[f*4096 + j2*64 + i2] = M[i2*65 + j2];
    }
}

// ---------------- standalone forward FFT of a real field -> canonical Tf ---
__global__ __launch_bounds__(256) void k_fft(const float* __restrict__ in,
                                             float2* __restrict__ Tf) {
    __shared__ float  tre[16][81];
    __shared__ float2 S[16][81];
    int tid = threadIdx.x;
    int img0 = blockIdx.x * 16;
    int tl = tid & 15, th = tid >> 4;
    int gb = (img0 + th)*81;
    #pragma unroll
    for (int k = 0; k < 6; k++) {
        int p = tl + 16*k;
        if (p < 81) tre[th][p] = in[gb + p];
    }
    __syncthreads();
    #pragma unroll
    for (int k = 0; k < 6; k++) {
        int idx = tl + 16*k;
        if (idx < 81) {
            int r = idx/9, ky = idx%9;
            float sr = 0.f, si = 0.f;
            int tt = 0;
            #pragma unroll
            for (int xx = 0; xx < 9; xx++) {
                float v = tre[th][r*9 + xx];
                sr += v*COS9[tt]; si -= v*SIN9[tt];
                tt += ky; if (tt >= 9) tt -= 9;
            }
            S[th][idx] = make_float2(sr, si);
        }
    }
    __syncthreads();
    #pragma unroll
    for (int k = 0; k < 3; k++) {
        int l = th + 16*k;
        if (l < NCAN) {
            int f = CANON(l);
            int kx = f/9, ky = f%9;
            float fr = 0.f, fim = 0.f;
            int tt = 0;
            #pragma unroll
            for (int r = 0; r < 9; r++) {
                float2 s = S[tl][r*9 + ky];
                float c = COS9[tt], sn = SIN9[tt];
                fr  += s.x*c + s.y*sn;
                fim += s.y*c - s.x*sn;
                tt += kx; if (tt >= 9) tt -= 9;
            }
            Tf[f*NIMG + img0 + tl] = make_float2(fr, fim);
        }
    }
}

// ---------------- per-frequency matvec, LDS-free ---------------------------
// lane = output channel (coalesced V reads); batch index wave-uniform
// (scalar T loads). Y[f][b*64+o] = sum_c V[f][c*64+o] * T[f][b*64+c].
__global__ __launch_bounds__(256) void k_mv(const float2* __restrict__ Tf,
                                            float2* __restrict__ Yf,
                                            const float2* __restrict__ V) {
    int l = blockIdx.x >> 3, bc = blockIdx.x & 7;   // 41 freqs x 8 chunks
    int f = CANON(l);
    int lane = threadIdx.x & 63;
    int wid  = __builtin_amdgcn_readfirstlane((int)(threadIdx.x >> 6));
    int b0 = bc*32 + wid*8;                          // 8 batches per wave
    const float2* Vg = V + f*4096 + lane;
    const float2* Tg = Tf + f*NIMG + b0*64;
    float2 acc[8];
    #pragma unroll
    for (int j = 0; j < 8; ++j) acc[j] = make_float2(0.f, 0.f);
    #pragma unroll 4
    for (int c = 0; c < 64; ++c) {
        float2 v = Vg[c*64];
        #pragma unroll
        for (int j = 0; j < 8; ++j) {
            float2 t = Tg[j*64 + c];                 // wave-uniform -> s_load
            acc[j].x += v.x*t.x - v.y*t.y;
            acc[j].y += v.x*t.y + v.y*t.x;
        }
    }
    float2* Yg = Yf + f*NIMG + b0*64 + lane;
    #pragma unroll
    for (int j = 0; j < 8; ++j) Yg[j*64] = acc[j];
}

// ---------------- fused: finv(iter) + ffwd(iter+1) -------------------------
__global__ __launch_bounds__(256) void k_fuse(const float2* __restrict__ Yf,
                                              float* __restrict__ u12g,
                                              float* __restrict__ zg,
                                              const float* __restrict__ bias,
                                              float2* __restrict__ Tf) {
    __shared__ float2 Yc[16][81];
    __shared__ float2 T1[16][81];
    __shared__ float  zl[16][81];
    __shared__ float  ul[16][81];
    __shared__ float2 tw81[81];        // tw81[a*9+b] = (cos,sin)(2*pi*(a*b%9)/9)
    int tid = threadIdx.x;
    for (int i = tid; i < 81; i += 256) {
        int t = ((i/9)*(i%9)) % 9;
        tw81[i] = make_float2(COS9[t], SIN9[t]);
    }
    int img0 = blockIdx.x * 16;
    int tl = tid & 15, th = tid >> 4;
    // load canonical freqs; reconstruct mirrors by conjugation (field real)
    #pragma unroll
    for (int k = 0; k < 3; k++) {
        int l = th + 16*k;
        if (l < NCAN) {
            int f = CANON(l);
            float2 a = Yf[f*NIMG + img0 + tl];
            Yc[tl][f] = a;
            int xx = f/9, yy = f%9;
            int fm = ((9-xx)%9)*9 + (9-yy)%9;
            if (fm != f) Yc[tl][fm] = make_float2(a.x, -a.y);
        }
    }
    __syncthreads();
    // IFFT stage 1: T1[r][ky] = sum_kx Yc[kx][ky] * w^{+ r kx}
    #pragma unroll
    for (int k = 0; k < 6; k++) {
        int idx = tl + 16*k;
        if (idx < 81) {
            int r = idx/9, ky = idx%9;
            float sr = 0.f, si = 0.f;
            #pragma unroll
            for (int kx = 0; kx < 9; kx++) {
                float2 a = Yc[th][kx*9 + ky];
                float2 w = tw81[r*9 + kx];
                sr += a.x*w.x - a.y*w.y;
                si += a.x*w.y + a.y*w.x;
            }
            T1[th][idx] = make_float2(sr, si);
        }
    }
    __syncthreads();
    // IFFT stage 2 + PR update (z,u kept in LDS)
    int gb = (img0 + th)*81;
    #pragma unroll
    for (int k = 0; k < 6; k++) {
        int p = tl + 16*k;
        if (p < 81) {
            int r = p/9, xc = p%9;
            float yr = 0.f;
            #pragma unroll
            for (int ky = 0; ky < 9; ky++) {
                float2 a = T1[th][r*9 + ky];
                float2 w = tw81[xc*9 + ky];
                yr += a.x*w.x - a.y*w.y;
            }
            yr *= (1.f/81.f);
            bool interior = (r >= 1 && r <= 7 && xc >= 1 && xc <= 7);
            float un = 2.f*yr - u12g[gb+p];
            float zn = interior ? fmaxf(un, 0.f) : 0.f;
            zl[th][p] = zn; ul[th][p] = un;
            zg[gb+p] = zn;
        }
    }
    __syncthreads();
    // phase B: u12' = 2z-u ; FFT2(u12'+bias) -> Tf
    float* tre = (float*)Yc;           // alias (Yc dead)
    #pragma unroll
    for (int k = 0; k < 6; k++) {
        int p = tl + 16*k;
        if (p < 81) {
            float v = 2.f*zl[th][p] - ul[th][p];
            u12g[gb+p] = v;
            tre[th*81 + p] = v + bias[gb+p];
        }
    }
    __syncthreads();
    float2* S = (float2*)T1;           // alias (T1 dead)
    #pragma unroll
    for (int k = 0; k < 6; k++) {
        int idx = tl + 16*k;
        if (idx < 81) {
            int r = idx/9, ky = idx%9;
            float sr = 0.f, si = 0.f;
            #pragma unroll
            for (int xx = 0; xx < 9; xx++) {
                float v = tre[th*81 + r*9 + xx];
                float2 w = tw81[ky*9 + xx];
                sr += v*w.x; si -= v*w.y;
            }
            S[th*81 + idx] = make_float2(sr, si);
        }
    }
    __syncthreads();
    #pragma unroll
    for (int k = 0; k < 3; k++) {
        int l = th + 16*k;
        if (l < NCAN) {
            int f = CANON(l);
            int kx = f/9, ky = f%9;
            float fr = 0.f, fim = 0.f;
            #pragma unroll
            for (int r = 0; r < 9; r++) {
                float2 s = S[tl*81 + r*9 + ky];
                float2 w = tw81[kx*9 + r];
                fr  += s.x*w.x + s.y*w.y;
                fim += s.y*w.x - s.x*w.y;
            }
            Tf[f*NIMG + img0 + tl] = make_float2(fr, fim);
        }
    }
}

// ---------------- final: IFFT(W z) -> relu(+bias) masked -> crop write -----
__global__ __launch_bounds__(256) void k_crop(const float2* __restrict__ Yf,
                                              const float* __restrict__ bias,
                                              float* __restrict__ zc) {
    __shared__ float2 Yc[16][81];
    __shared__ float2 T1[16][81];
    int tid = threadIdx.x;
    int img0 = blockIdx.x * 16;
    int tl = tid & 15, th = tid >> 4;
    #pragma unroll
    for (int k = 0; k < 3; k++) {
        int l = th + 16*k;
        if (l < NCAN) {
            int f = CANON(l);
            float2 a = Yf[f*NIMG + img0 + tl];
            Yc[tl][f] = a;
            int xx = f/9, yy = f%9;
            int fm = ((9-xx)%9)*9 + (9-yy)%9;
            if (fm != f) Yc[tl][fm] = make_float2(a.x, -a.y);
        }
    }
    __syncthreads();
    #pragma unroll
    for (int k = 0; k < 6; k++) {
        int idx = tl + 16*k;
        if (idx < 81) {
            int r = idx/9, ky = idx%9;
            float sr = 0.f, si = 0.f;
            int tt = 0;
            #pragma unroll
            for (int kx = 0; kx < 9; kx++) {
                float2 a = Yc[th][kx*9 + ky];
                float c = COS9[tt], sn = SIN9[tt];
                sr += a.x*c - a.y*sn;
                si += a.x*sn + a.y*c;
                tt += r; if (tt >= 9) tt -= 9;
            }
            T1[th][idx] = make_float2(sr, si);
        }
    }
    __syncthreads();
    int gb = (img0 + th)*81;
    #pragma unroll
    for (int k = 0; k < 6; k++) {
        int p = tl + 16*k;
        if (p < 81) {
            int r = p/9, xc = p%9;
            if (r >= 1 && r <= 7 && xc >= 1 && xc <= 7) {
                float yr = 0.f;
                int tt = 0;
                #pragma unroll
                for (int ky = 0; ky < 9; ky++) {
                    float2 a = T1[th][r*9 + ky];
                    yr += a.x*COS9[tt] - a.y*SIN9[tt];
                    tt += xc; if (tt >= 9) tt -= 9;
                }
                yr *= (1.f/81.f);
                float zn = fmaxf(yr + bias[gb+p], 0.f);
                int img = img0 + th;
                zc[(img >> 6)*3136 + (img & 63)*49 + (r-1)*7 + (xc-1)] = zn;
            }
        }
    }
}

// ---------------- fc1: (256x3136)x(512x3136)^T + b, relu -------------------
__global__ __launch_bounds__(256) void k_fc1(const float* __restrict__ A,
                                             const float* __restrict__ W,
                                             const float* __restrict__ bb,
                                             float* __restrict__ H) {
    int bt = blockIdx.x >> 5, ot = blockIdx.x & 31;
    int b0 = bt*16, o0 = ot*16;
    __shared__ float At[16][65], Bt[16][65];
    int tid = threadIdx.x;
    int row = tid >> 6, col = tid & 63;
    int tb = tid >> 4, to = tid & 15;
    float acc = 0.f;
    for (int k0 = 0; k0 < 3136; k0 += 64) {
        #pragma unroll
        for (int s = 0; s < 4; s++) {
            int rr = row + s*4;
            At[rr][col] = A[(b0+rr)*3136 + k0 + col];
            Bt[rr][col] = W[(o0+rr)*3136 + k0 + col];
        }
        __syncthreads();
        #pragma unroll
        for (int kk = 0; kk < 64; kk++)
            acc += At[tb][kk] * Bt[to][kk];
        __syncthreads();
    }
    H[(b0+tb)*512 + o0+to] = fmaxf(acc + bb[o0+to], 0.f);
}

// ---------------- fc2: (256x512)x(18x512)^T + b ----------------------------
__global__ __launch_bounds__(256) void k_fc2(const float* __restrict__ H,
                                             const float* __restrict__ W,
                                             const float* __restrict__ bb,
                                             float* __restrict__ out) {
    int idx = blockIdx.x*256 + threadIdx.x;
    if (idx >= 4608) return;
    int b = idx/18, o = idx%18;
    const float* h = H + b*512;
    const float* w = W + o*512;
    float acc = 0.f;
    for (int k = 0; k < 512; k++) acc += h[k]*w[k];
    out[idx] = acc + bb[o];
}

// ---------------------------------------------------------------------------
extern "C" void kernel_launch(void* const* d_in, const int* in_sizes, int n_in,
                              void* d_out, int out_size, void* d_ws, size_t ws_size,
                              hipStream_t stream) {
    (void)in_sizes; (void)n_in; (void)out_size; (void)ws_size;
    const float* x   = (const float*)d_in[0];
    const float* c1w = (const float*)d_in[1];
    const float* c1b = (const float*)d_in[2];
    const float* c2w = (const float*)d_in[3];
    const float* c2b = (const float*)d_in[4];
    const float* Uw  = (const float*)d_in[5];
    const float* Ub  = (const float*)d_in[6];
    const float* Aw  = (const float*)d_in[7];
    const float* gp  = (const float*)d_in[8];
    const float* f1w = (const float*)d_in[9];
    const float* f1b = (const float*)d_in[10];
    const float* f2w = (const float*)d_in[11];
    const float* f2b = (const float*)d_in[12];

    float* ws = (float*)d_ws;
    float*  h1   = ws + 0;                       // 3,276,800 f
    float2* Tf   = (float2*)(ws + 0);            // alias h1 (dead after k_cvb)
    float*  bias = ws + 3276800;                 // 1,327,104 f
    float*  z    = ws + 4603904;                 // 1,327,104 f
    float*  u12  = ws + 5931008;                 // 1,327,104 f
    float2* Yf   = (float2*)(ws + 7258112);      // 1,327,104 c2
    float2* Af   = (float2*)(ws + 9912320);      // 331,776 c2
    float2* Minv = (float2*)(ws + 10575872);     // 331,776 c2
    float2* WmT  = (float2*)(ws + 11239424);     // 331,776 c2
    float*  zc   = ws + 11902976;                // 802,816 f
    float*  hfc  = ws + 12705792;                // 131,072 f
    float*  sc   = ws + 12836864;                // 2 f

    hipMemsetAsync(z, 0, (size_t)2*1327104*sizeof(float), stream);   // z, u12

    k_norm <<<1,   256, 0, stream>>>(Aw, sc);
    k_conv1<<<256, 512, 0, stream>>>(x, c1w, c1b, h1);
    k_cvb  <<<256, 256, 0, stream>>>(h1, c2w, c2b, Uw, Ub, bias);
    k_af   <<<NCAN,256, 0, stream>>>(Aw, sc, Af);
    k_mw   <<<NCAN,256, 0, stream>>>(Af, gp, Minv, WmT);
    k_inv  <<<NCAN,256, 0, stream>>>(Minv);

    // iteration 0 forward: u12 = 0, so T = FFT(bias)
    k_fft<<<1024,256,0,stream>>>(bias, Tf);
    for (int it = 0; it < MAXIT; it++) {
        k_mv  <<<NCAN*8,256,0,stream>>>(Tf, Yf, Minv);
        k_fuse<<<1024,  256,0,stream>>>(Yf, u12, z, bias, Tf);
    }
    // final pass: brelu(W z + bias) -> crop
    k_fft <<<1024,  256,0,stream>>>(z, Tf);
    k_mv  <<<NCAN*8,256,0,stream>>>(Tf, Yf, WmT);
    k_crop<<<1024,  256,0,stream>>>(Yf, bias, zc);

    k_fc1<<<512,256,0,stream>>>(zc, f1w, f1b, hfc);
    k_fc2<<<18, 256,0,stream>>>(hfc, f2w, f2b, (float*)d_out);
}